// Round 3
// baseline (238.150 us; speedup 1.0000x reference)
//
#include <hip/hip_runtime.h>
#include <hip/hip_fp16.h>

// Problem constants
#define S_LEN 128
#define DLOG  128
#define DMEM  16
#define SO    120
#define HDIM  256

typedef _Float16 v8h __attribute__((ext_vector_type(8)));
typedef __fp16 v2hf __attribute__((ext_vector_type(2)));
typedef float v4f __attribute__((ext_vector_type(4)));

union PkU { v2hf h; unsigned u; };
union V8U { v8h v; int u[4]; };

__device__ __forceinline__ v8h splat8(float x) {
  _Float16 h = (_Float16)x;
  v8h v = {h, h, h, h, h, h, h, h};
  return v;
}

// ---------------------------------------------------------------------------
// K1: Q = x@Wq^T + bq,  K = x@Wk^T + bk,  u = x@W1^T  (512 thr, 1 dot each)
// u[bj][o] (o<256) replaces the old h-GEMM:  delta@W1^T = u[j] - u[i].
// ---------------------------------------------------------------------------
__global__ __launch_bounds__(512) void qku_kernel(
    const float* __restrict__ xl, const float* __restrict__ Wq,
    const float* __restrict__ bq, const float* __restrict__ Wk,
    const float* __restrict__ bk, const float* __restrict__ W1,
    float* __restrict__ Q, float* __restrict__ K, float* __restrict__ u) {
  int bj = blockIdx.x, t = threadIdx.x;
  __shared__ float xs[128];
  if (t < 128) xs[t] = xl[bj * 128 + t];
  __syncthreads();
  const float* wr;
  float acc;
  int o;
  if (t < 128) {
    o = t; wr = Wq + o * 128; acc = bq[o];
  } else if (t < 256) {
    o = t - 128; wr = Wk + o * 128; acc = bk[o];
  } else {
    o = t - 256; wr = W1 + o * 128; acc = 0.f;
  }
  #pragma unroll 4
  for (int d = 0; d < 128; ++d) acc = fmaf(xs[d], wr[d], acc);
  if (t < 128) Q[bj * 128 + o] = acc;
  else if (t < 256) K[bj * 128 + o] = acc;
  else u[bj * 256 + o] = acc;
}

// ---------------------------------------------------------------------------
// K2: attn[b,j,i] = softmax_i( Q[b,j].K[b,i] / sqrt(128) )
// ---------------------------------------------------------------------------
__global__ __launch_bounds__(128) void attn_kernel(
    const float* __restrict__ Q, const float* __restrict__ K,
    float* __restrict__ attn) {
  int bj = blockIdx.x, b = bj >> 7, i = threadIdx.x;
  __shared__ float qs[128];
  __shared__ float red[128];
  qs[i] = Q[bj * 128 + i];
  __syncthreads();
  const float* kr = K + (b * 128 + i) * 128;
  float s = 0.f;
  #pragma unroll 4
  for (int d = 0; d < 128; ++d) s = fmaf(qs[d], kr[d], s);
  s *= 0.08838834764831845f;  // 1/sqrt(128)
  red[i] = s;
  __syncthreads();
  for (int off = 64; off; off >>= 1) {
    if (i < off) red[i] = fmaxf(red[i], red[i + off]);
    __syncthreads();
  }
  float m = red[0];
  __syncthreads();
  float e = expf(s - m);
  red[i] = e;
  __syncthreads();
  for (int off = 64; off; off >>= 1) {
    if (i < off) red[i] += red[i + off];
    __syncthreads();
  }
  attn[(size_t)bj * 128 + i] = e / red[0];
}

// ---------------------------------------------------------------------------
// K3 (fused h+lie): per block, 64 pairs p = blk*64 + [0,64), all same (b,j),
// i = i0 + [0,64).  Per K-half:
//   h[i][kk] = tanh(u[bj][kk] - u[b,i][kk] + b1[kk])  (f16 tile in LDS)
//   lie[p][n] += h[p] . W2[n]   (f16 MFMA, W2 half staged in LDS)
// lie + b2 written f16 to slot bytes [512,752).  No h round-trip through HBM.
// ---------------------------------------------------------------------------
__global__ __launch_bounds__(256) void lie_kernel(
    const float* __restrict__ W2g, const float* __restrict__ b2g,
    const float* __restrict__ ug, const float* __restrict__ b1g,
    float* __restrict__ Tg) {
  __shared__ _Float16 w2t[128 * 136];
  __shared__ _Float16 ht[64 * 136];
  __shared__ float b1s[128];
  __shared__ float ujs[128];
  int t = threadIdx.x, lane = t & 63;
  int wu = __builtin_amdgcn_readfirstlane(t >> 6);
  int blk = blockIdx.x;
  int bj = blk >> 1;
  int i0 = (blk & 1) << 6;
  int b = bj >> 7;
  int pbase = blk * 64 + wu * 16;
  int nn = lane & 15, q = lane >> 4;

  v4f acc[8];
  #pragma unroll
  for (int tt = 0; tt < 8; ++tt) acc[tt] = (v4f){0.f, 0.f, 0.f, 0.f};

  for (int khalf = 0; khalf < 2; ++khalf) {
    __syncthreads();
    // stage W2 K-half (120 rows + 8 zero-pad rows)
    for (int idx = t; idx < 120 * 128; idx += 256) {
      int o = idx >> 7, kk = idx & 127;
      w2t[o * 136 + kk] = (_Float16)W2g[o * 256 + khalf * 128 + kk];
    }
    for (int idx = t; idx < 8 * 128; idx += 256)
      w2t[(120 + (idx >> 7)) * 136 + (idx & 127)] = (_Float16)0.f;
    // stage b1 and u[bj] K-halves
    if (t < 128) b1s[t] = b1g[khalf * 128 + t];
    else ujs[t - 128] = ug[bj * 256 + khalf * 128 + (t - 128)];
    __syncthreads();
    // compute h tile on the fly: 64 pairs x 128 k
    for (int idx = t; idx < 64 * 128; idx += 256) {
      int i = idx >> 7, kk = idx & 127;
      float x = ujs[kk] + b1s[kk] -
                ug[(size_t)(b * 128 + i0 + i) * 256 + khalf * 128 + kk];
      float ax = fabsf(x);
      float e = __expf(-2.f * ax);
      float r = __fdividef(1.f - e, 1.f + e);
      ht[i * 136 + kk] = (_Float16)copysignf(r, x);
    }
    __syncthreads();
    #pragma unroll
    for (int ks = 0; ks < 4; ++ks) {
      v8h ah = *(const v8h*)&ht[(wu * 16 + nn) * 136 + ks * 32 + 8 * q];
      #pragma unroll
      for (int tt = 0; tt < 8; ++tt) {
        const v8h bf = *(const v8h*)(w2t + (16 * tt + nn) * 136 + ks * 32 + 8 * q);
        acc[tt] = __builtin_amdgcn_mfma_f32_16x16x32_f16(ah, bf, acc[tt], 0, 0, 0);
      }
    }
  }

  _Float16* hw = (_Float16*)Tg;
  #pragma unroll
  for (int tt = 0; tt < 8; ++tt) {
    int n16 = 16 * tt + nn;
    if (n16 < 120) {
      float bb = b2g[n16];
      #pragma unroll
      for (int reg = 0; reg < 4; ++reg) {
        size_t p = (size_t)(pbase + 4 * q + reg);
        hw[p * 512 + 256 + n16] = (_Float16)(acc[tt][reg] + bb);
      }
    }
  }
}

// ---------------------------------------------------------------------------
// K4: per-pair T = expm(skew(lie)) via Paterson-Stockmeyer even/odd split:
//   exp(A) = C(B) + A*Q(B),  B = A^2 (SYMMETRIC -> one bpermute transform
//   serves as BOTH MFMA operands).
// Epilogue computes attn-weighted transported partials (per-block) to `part`.
// ---------------------------------------------------------------------------
__device__ __forceinline__ void split8(const float* x, v8h& hi, v8h& lo) {
  union U { v8h v; v2hf p[4]; } H, L;
  #pragma unroll
  for (int i = 0; i < 4; ++i) {
    float a = x[2 * i], b = x[2 * i + 1];
    v2hf h = __builtin_amdgcn_cvt_pkrtz(a, b);
    float ra = (float)h[0], rb = (float)h[1];
    v2hf l = __builtin_amdgcn_cvt_pkrtz(a - ra, b - rb);
    H.p[i] = h;
    L.p[i] = l;
  }
  hi = H.v;
  lo = L.v;
}

__device__ __forceinline__ int lie_idx(int rr, int cc) {
  return 15 * rr - ((rr * (rr - 1)) >> 1) + cc - rr - 1;
}

__global__ __launch_bounds__(256) void expm_kernel(
    float* __restrict__ Tg, const float* __restrict__ attn,
    const float* __restrict__ xm, float* __restrict__ part) {
  __shared__ char lds[12288] __attribute__((aligned(16)));
  __shared__ float sred[4][16];
  int t = threadIdx.x, lane = t & 63;
  int wu = __builtin_amdgcn_readfirstlane(t >> 6);
  int pbase = blockIdx.x * 8 + wu * 2;
  int nn = lane & 15, q = lane >> 4, b8 = (q & 1) * 8;
  char* wb = lds + wu * 3072;
  _Float16* lieS = (_Float16*)wb;   // [2][128] f16
  float* ErB = (float*)(wb + 512);  // [2][320] f32 (16 rows x stride 20)
  const _Float16* hf = (const _Float16*)Tg;

  int idxA = ((2 * (q & 1)) * 16 + nn) * 4;
  int idxB = idxA + 64;

  // ---- load lie, compute per-pair scaling ----
  float scv[2];
  int sv[2];
  #pragma unroll
  for (int j = 0; j < 2; ++j) {
    size_t p = (size_t)(pbase + j);
    _Float16 a0 = (lane < 120) ? hf[p * 512 + 256 + lane] : (_Float16)0.f;
    _Float16 a1 = (lane < 56) ? hf[p * 512 + 320 + lane] : (_Float16)0.f;
    lieS[j * 128 + lane] = a0;
    lieS[j * 128 + 64 + lane] = a1;
    float f0 = (float)a0, f1 = (float)a1;
    float s2 = f0 * f0 + f1 * f1;
    #pragma unroll
    for (int off = 1; off < 64; off <<= 1) s2 += __shfl_xor(s2, off, 64);
    float bound = sqrtf(s2);  // ||A||_2 <= sqrt(sum lie^2) for skew
    int s = 0;
    while (bound > 1.0f && s < 12) { bound *= 0.5f; s++; }
    sv[j] = __builtin_amdgcn_readfirstlane(s);
    scv[j] = ldexpf(1.0f, -s);
  }
  asm volatile("s_waitcnt lgkmcnt(0)" ::: "memory");

  // ---- A-frags (f16-exact, [X|X] dup) + f32 C-layout rows of A ----
  V8U Apk[2], BfA[2];
  v4f Af[2];
  #pragma unroll
  for (int j = 0; j < 2; ++j) {
    const _Float16* lp = lieS + j * 128;
    float sc = scv[j];
    float av[8];
    #pragma unroll
    for (int jj = 0; jj < 8; ++jj) {
      int c = b8 + jj;
      int rr = min(nn, c), c2 = max(nn, c);
      float lv = (c == nn) ? 0.f : (float)lp[lie_idx(rr, c2)];
      av[jj] = (c == nn) ? 0.f : ((c > nn) ? lv : -lv) * sc;
    }
    #pragma unroll
    for (int i = 0; i < 4; ++i) {
      PkU u;
      u.h = __builtin_amdgcn_cvt_pkrtz(av[2 * i], av[2 * i + 1]);
      Apk[j].u[i] = (int)u.u;
      BfA[j].u[i] = Apk[j].u[i] ^ 0x80008000;  // B-frag of A (= -A rows)
    }
    #pragma unroll
    for (int reg = 0; reg < 4; ++reg) {
      int r = 4 * q + reg;
      int rr = min(r, nn), c2 = max(r, nn);
      float lv = (r == nn) ? 0.f : (float)lp[lie_idx(rr, c2)];
      Af[j][reg] = (r == nn) ? 0.f : ((nn > r) ? lv : -lv) * sc;
    }
  }

  // identity frags in gather layout, pre-scaled by combo coefficients
  V8U IC1, IC2;
  #pragma unroll
  for (int i = 0; i < 4; ++i) {
    float d0 = (b8 + 2 * i == nn) ? 1.f : 0.f;
    float d1 = (b8 + 2 * i + 1 == nn) ? 1.f : 0.f;
    PkU u1, u2;
    u1.h = __builtin_amdgcn_cvt_pkrtz(10.666667f * d0, 10.666667f * d1);   // 256/24
    u2.h = __builtin_amdgcn_cvt_pkrtz(2.1333333f * d0, 2.1333333f * d1);   // 256/120
    IC1.u[i] = (int)u1.u;
    IC2.u[i] = (int)u2.u;
  }

  v4f z4 = {0.f, 0.f, 0.f, 0.f};

  // ---- MFMA1: cB = 2*B (B = A^2) ----
  v4f cB[2];
  #pragma unroll
  for (int j = 0; j < 2; ++j)
    cB[j] = __builtin_amdgcn_mfma_f32_16x16x32_f16(Apk[j].v, BfA[j].v, z4, 0, 0, 0);

  // ---- transform 1: fB = gather(2B) ----
  V8U fB[2];
  #pragma unroll
  for (int j = 0; j < 2; ++j) {
    PkU u0, u1;
    u0.h = __builtin_amdgcn_cvt_pkrtz(cB[j][0], cB[j][1]);
    u1.h = __builtin_amdgcn_cvt_pkrtz(cB[j][2], cB[j][3]);
    fB[j].u[0] = __builtin_amdgcn_ds_bpermute(idxA, (int)u0.u);
    fB[j].u[1] = __builtin_amdgcn_ds_bpermute(idxA, (int)u1.u);
    fB[j].u[2] = __builtin_amdgcn_ds_bpermute(idxB, (int)u0.u);
    fB[j].u[3] = __builtin_amdgcn_ds_bpermute(idxB, (int)u1.u);
  }

  // ---- MFMA2: cB2 = 8*B^2 ----
  v4f cB2[2];
  #pragma unroll
  for (int j = 0; j < 2; ++j)
    cB2[j] = __builtin_amdgcn_mfma_f32_16x16x32_f16(fB[j].v, fB[j].v, z4, 0, 0, 0);

  // ---- transform 2: fB2 = gather(8*B^2) ----
  V8U fB2[2];
  #pragma unroll
  for (int j = 0; j < 2; ++j) {
    PkU u0, u1;
    u0.h = __builtin_amdgcn_cvt_pkrtz(cB2[j][0], cB2[j][1]);
    u1.h = __builtin_amdgcn_cvt_pkrtz(cB2[j][2], cB2[j][3]);
    fB2[j].u[0] = __builtin_amdgcn_ds_bpermute(idxA, (int)u0.u);
    fB2[j].u[1] = __builtin_amdgcn_ds_bpermute(idxA, (int)u1.u);
    fB2[j].u[2] = __builtin_amdgcn_ds_bpermute(idxB, (int)u0.u);
    fB2[j].u[3] = __builtin_amdgcn_ds_bpermute(idxB, (int)u1.u);
  }

  // ---- combo frags in f16 domain ----
  v8h k1a = splat8(7.9365079e-4f);   // 32/40320
  v8h k1b = splat8(0.17777778f);     // 128/720
  v8h k2a = splat8(8.8183422e-5f);   // 32/362880
  v8h k2b = splat8(2.5396825e-2f);   // 128/5040
  V8U M1[2], M2[2];
  #pragma unroll
  for (int j = 0; j < 2; ++j) {
    M1[j].v = fB2[j].v * k1a + (fB[j].v * k1b + IC1.v);
    M2[j].v = fB2[j].v * k2a + (fB[j].v * k2b + IC2.v);
  }

  // ---- MFMA3/4: high parts of C and Q; fold exact low-order f32 terms ----
  v4f Cc[2], Qc[2];
  #pragma unroll
  for (int j = 0; j < 2; ++j) {
    v4f c3m = __builtin_amdgcn_mfma_f32_16x16x32_f16(M1[j].v, fB2[j].v, z4, 0, 0, 0);
    v4f c4m = __builtin_amdgcn_mfma_f32_16x16x32_f16(M2[j].v, fB2[j].v, z4, 0, 0, 0);
    #pragma unroll
    for (int reg = 0; reg < 4; ++reg) {
      float dg = (4 * q + reg == nn) ? 1.f : 0.f;
      Cc[j][reg] = fmaf(c3m[reg], 2.44140625e-4f,
                        fmaf(cB[j][reg], 0.25f, dg + Af[j][reg]));
      Qc[j][reg] = fmaf(c4m[reg], 2.44140625e-4f, cB[j][reg] * 0.083333333f);
    }
  }

  // ---- transform 3: fQ = gather(Qr) ----
  V8U fQ[2];
  #pragma unroll
  for (int j = 0; j < 2; ++j) {
    PkU u0, u1;
    u0.h = __builtin_amdgcn_cvt_pkrtz(Qc[j][0], Qc[j][1]);
    u1.h = __builtin_amdgcn_cvt_pkrtz(Qc[j][2], Qc[j][3]);
    fQ[j].u[0] = __builtin_amdgcn_ds_bpermute(idxA, (int)u0.u);
    fQ[j].u[1] = __builtin_amdgcn_ds_bpermute(idxA, (int)u1.u);
    fQ[j].u[2] = __builtin_amdgcn_ds_bpermute(idxB, (int)u0.u);
    fQ[j].u[3] = __builtin_amdgcn_ds_bpermute(idxB, (int)u1.u);
  }

  // ---- MFMA5: E = Cc + A*Qr ----
  v4f E[2];
  #pragma unroll
  for (int j = 0; j < 2; ++j) {
    v4f c5 = __builtin_amdgcn_mfma_f32_16x16x32_f16(Apk[j].v, fQ[j].v, z4, 0, 0, 0);
    E[j] = Cc[j] + c5 * 0.5f;
  }

  // ---- squarings: E <- E*E ----
  int smax = max(sv[0], sv[1]);
  for (int it = 0; it < smax; ++it) {
    #pragma unroll
    for (int j = 0; j < 2; ++j) {
      if (it < sv[j]) {
        float* Erp = ErB + j * 320;
        PkU u0, u1;
        u0.h = __builtin_amdgcn_cvt_pkrtz(E[j][0], E[j][1]);
        u1.h = __builtin_amdgcn_cvt_pkrtz(E[j][2], E[j][3]);
        V8U bfe;
        bfe.u[0] = __builtin_amdgcn_ds_bpermute(idxA, (int)u0.u);
        bfe.u[1] = __builtin_amdgcn_ds_bpermute(idxA, (int)u1.u);
        bfe.u[2] = __builtin_amdgcn_ds_bpermute(idxB, (int)u0.u);
        bfe.u[3] = __builtin_amdgcn_ds_bpermute(idxB, (int)u1.u);
        #pragma unroll
        for (int reg = 0; reg < 4; ++reg)
          Erp[(4 * q + reg) * 20 + nn] = E[j][reg];
        asm volatile("s_waitcnt lgkmcnt(0)" ::: "memory");
        float4 a0 = *(const float4*)(Erp + nn * 20 + b8);
        float4 a1 = *(const float4*)(Erp + nn * 20 + b8 + 4);
        float xa[8] = {a0.x, a0.y, a0.z, a0.w, a1.x, a1.y, a1.z, a1.w};
        v8h ahi, alo;
        split8(xa, ahi, alo);
        v8h Ecat = (q < 2) ? ahi : alo;
        v4f z = {0.f, 0.f, 0.f, 0.f};
        E[j] = __builtin_amdgcn_mfma_f32_16x16x32_f16(Ecat, bfe.v, z, 0, 0, 0);
      }
    }
  }

  // ---- store T + fused attn-weighted transported partials ----
  float pacc[4] = {0.f, 0.f, 0.f, 0.f};
  #pragma unroll
  for (int j = 0; j < 2; ++j) {
    int p = pbase + j;
    float* dst = Tg + (size_t)p * 256;
    #pragma unroll
    for (int reg = 0; reg < 4; ++reg)
      dst[(4 * q + reg) * 16 + nn] = E[j][reg];
    int b = p >> 14, i = p & 127;
    float xv = xm[((b << 7) + i) * 16 + nn];
    float aw = attn[(size_t)p] * xv;
    #pragma unroll
    for (int reg = 0; reg < 4; ++reg)
      pacc[reg] = fmaf(aw, E[j][reg], pacc[reg]);
  }
  #pragma unroll
  for (int reg = 0; reg < 4; ++reg) {
    #pragma unroll
    for (int off = 1; off < 16; off <<= 1)
      pacc[reg] += __shfl_xor(pacc[reg], off, 64);
  }
  if (nn == 0) {
    #pragma unroll
    for (int reg = 0; reg < 4; ++reg) sred[wu][4 * q + reg] = pacc[reg];
  }
  __syncthreads();
  if (t < 16)
    part[(size_t)blockIdx.x * 16 + t] =
        sred[0][t] + sred[1][t] + sred[2][t] + sred[3][t];
}

// ---------------------------------------------------------------------------
// K5: settled[bj] = sum of 16 per-block partials; out = settled @ Wo^T + bo
// ---------------------------------------------------------------------------
__global__ __launch_bounds__(64) void settle_fin_kernel(
    const float* __restrict__ part, const float* __restrict__ Wo,
    const float* __restrict__ bo, float* __restrict__ outp) {
  int bj = blockIdx.x, t = threadIdx.x;
  int r = t & 15, e0 = t >> 4;
  const float* pb = part + (size_t)bj * 256;
  float s = pb[e0 * 16 + r] + pb[(e0 + 4) * 16 + r] +
            pb[(e0 + 8) * 16 + r] + pb[(e0 + 12) * 16 + r];
  __shared__ float sf[64];
  sf[t] = s;
  __syncthreads();
  if (t < 16) sf[t] = sf[t] + sf[16 + t] + sf[32 + t] + sf[48 + t];
  __syncthreads();
  if (t < 16) {
    float o = bo[t];
    const float* wr = Wo + t * 16;
    #pragma unroll
    for (int c = 0; c < 16; ++c) o = fmaf(wr[c], sf[c], o);
    outp[bj * 16 + t] = o;
  }
}

// ---------------------------------------------------------------------------
extern "C" void kernel_launch(void* const* d_in, const int* in_sizes, int n_in,
                              void* d_out, int out_size, void* d_ws,
                              size_t ws_size, hipStream_t stream) {
  const float* xl = (const float*)d_in[0];
  const float* xm = (const float*)d_in[1];
  const float* Wq = (const float*)d_in[2];
  const float* bq = (const float*)d_in[3];
  const float* Wk = (const float*)d_in[4];
  const float* bk = (const float*)d_in[5];
  const float* W1 = (const float*)d_in[6];
  const float* b1 = (const float*)d_in[7];
  const float* W2 = (const float*)d_in[8];
  const float* b2 = (const float*)d_in[9];
  const float* Wo = (const float*)d_in[10];
  const float* bo = (const float*)d_in[11];
  float* outp = (float*)d_out;
  float* Tg = outp + 8192;  // [65536][256]: lie f16 in slot bytes [512,752),
                            // then full slot overwritten with T fp32
  float* wsf = (float*)d_ws;
  float* Q = wsf;                // 65536
  float* K = wsf + 65536;        // 65536
  float* attn = wsf + 131072;    // 65536
  // u and part ALIAS the same region: u is written by qku (disp 1) and last
  // read by lie (disp 3); part is first written by expm (disp 4).  Keeps the
  // workspace footprint at the harness-validated 1.25 MB.
  float* u = wsf + 196608;       // 512*256 = 131072  (x@W1^T)
  float* part = wsf + 196608;    // 8192*16 = 131072

  hipLaunchKernelGGL(qku_kernel, dim3(512), dim3(512), 0, stream, xl, Wq, bq, Wk, bk, W1, Q, K, u);
  hipLaunchKernelGGL(attn_kernel, dim3(512), dim3(128), 0, stream, Q, K, attn);
  hipLaunchKernelGGL(lie_kernel, dim3(1024), dim3(256), 0, stream, W2, b2, u, b1, Tg);
  hipLaunchKernelGGL(expm_kernel, dim3(8192), dim3(256), 0, stream, Tg, attn, xm, part);
  hipLaunchKernelGGL(settle_fin_kernel, dim3(512), dim3(64), 0, stream, part, Wo, bo, outp);
}

// Round 4
// 204.118 us; speedup vs baseline: 1.1667x; 1.1667x over previous
//
#include <hip/hip_runtime.h>
#include <hip/hip_fp16.h>

// Problem constants
#define S_LEN 128
#define DLOG  128
#define DMEM  16
#define SO    120
#define HDIM  256

typedef _Float16 v8h __attribute__((ext_vector_type(8)));
typedef __fp16 v2hf __attribute__((ext_vector_type(2)));
typedef float v4f __attribute__((ext_vector_type(4)));

union PkU { v2hf h; unsigned u; };
union V8U { v8h v; int u[4]; };

__device__ __forceinline__ v8h splat8(float x) {
  _Float16 h = (_Float16)x;
  v8h v = {h, h, h, h, h, h, h, h};
  return v;
}

// ---------------------------------------------------------------------------
// K1: Q = x@Wq^T + bq,  K = x@Wk^T + bk,  u = x@W1^T  (512 thr, 1 dot each)
// ---------------------------------------------------------------------------
__global__ __launch_bounds__(512) void qku_kernel(
    const float* __restrict__ xl, const float* __restrict__ Wq,
    const float* __restrict__ bq, const float* __restrict__ Wk,
    const float* __restrict__ bk, const float* __restrict__ W1,
    float* __restrict__ Q, float* __restrict__ K, float* __restrict__ u) {
  int bj = blockIdx.x, t = threadIdx.x;
  __shared__ float xs[128];
  if (t < 128) xs[t] = xl[bj * 128 + t];
  __syncthreads();
  const float* wr;
  float acc;
  int o;
  if (t < 128) {
    o = t; wr = Wq + o * 128; acc = bq[o];
  } else if (t < 256) {
    o = t - 128; wr = Wk + o * 128; acc = bk[o];
  } else {
    o = t - 256; wr = W1 + o * 128; acc = 0.f;
  }
  #pragma unroll 4
  for (int d = 0; d < 128; ++d) acc = fmaf(xs[d], wr[d], acc);
  if (t < 128) Q[bj * 128 + o] = acc;
  else if (t < 256) K[bj * 128 + o] = acc;
  else u[bj * 256 + o] = acc;
}

// ---------------------------------------------------------------------------
// K2: attn[b,j,i] = softmax_i( Q[b,j].K[b,i] / sqrt(128) )
// ---------------------------------------------------------------------------
__global__ __launch_bounds__(128) void attn_kernel(
    const float* __restrict__ Q, const float* __restrict__ K,
    float* __restrict__ attn) {
  int bj = blockIdx.x, b = bj >> 7, i = threadIdx.x;
  __shared__ float qs[128];
  __shared__ float red[128];
  qs[i] = Q[bj * 128 + i];
  __syncthreads();
  const float* kr = K + (b * 128 + i) * 128;
  float s = 0.f;
  #pragma unroll 4
  for (int d = 0; d < 128; ++d) s = fmaf(qs[d], kr[d], s);
  s *= 0.08838834764831845f;  // 1/sqrt(128)
  red[i] = s;
  __syncthreads();
  for (int off = 64; off; off >>= 1) {
    if (i < off) red[i] = fmaxf(red[i], red[i + off]);
    __syncthreads();
  }
  float m = red[0];
  __syncthreads();
  float e = expf(s - m);
  red[i] = e;
  __syncthreads();
  for (int off = 64; off; off >>= 1) {
    if (i < off) red[i] += red[i + off];
    __syncthreads();
  }
  attn[(size_t)bj * 128 + i] = e / red[0];
}

// ---------------------------------------------------------------------------
// K3a: one-time W2 f32 -> f16 conversion (30720 elems), into dead Q region.
// ---------------------------------------------------------------------------
__global__ __launch_bounds__(256) void w2prep_kernel(
    const float* __restrict__ W2g, _Float16* __restrict__ w2h) {
  int idx = (blockIdx.x * 256 + threadIdx.x) * 4;  // 30 blocks * 256 * 4 = 30720
  float4 v = *(const float4*)(W2g + idx);
  PkU u0, u1;
  u0.h = __builtin_amdgcn_cvt_pkrtz(v.x, v.y);
  u1.h = __builtin_amdgcn_cvt_pkrtz(v.z, v.w);
  uint2 pk = {u0.u, u1.u};
  *(uint2*)(w2h + idx) = pk;
}

// ---------------------------------------------------------------------------
// K3b: h[p][o] = tanh(u[bj][o] - u[b,i][o] + b1[o]) streamed, f16 into the
// first 512 B of pair p's 1024-B T-slot.  Flat full-occupancy kernel:
// 2M v8h units; float4 loads (L2-hot u), 16 B/lane coalesced stores.
// ---------------------------------------------------------------------------
__global__ __launch_bounds__(256) void h_from_u_kernel(
    const float* __restrict__ u, const float* __restrict__ b1,
    _Float16* __restrict__ hG) {
  int tid = blockIdx.x * 256 + threadIdx.x;  // 2048 blocks -> 524288 threads
  #pragma unroll
  for (int g = 0; g < 4; ++g) {
    int unit = tid + g * 524288;     // 2097152 units total
    int p = unit >> 5;               // pair index
    int o0 = (unit & 31) * 8;        // o-chunk base
    int bj = p >> 7;
    int b = bj >> 7;
    int i = p & 127;
    const float* uj = u + bj * 256 + o0;
    const float* ui = u + (size_t)(b * 128 + i) * 256 + o0;
    const float* bb = b1 + o0;
    float4 j0 = *(const float4*)uj, j1 = *(const float4*)(uj + 4);
    float4 i0 = *(const float4*)ui, i1 = *(const float4*)(ui + 4);
    float4 c0 = *(const float4*)bb, c1 = *(const float4*)(bb + 4);
    float xv[8] = {j0.x - i0.x + c0.x, j0.y - i0.y + c0.y,
                   j0.z - i0.z + c0.z, j0.w - i0.w + c0.w,
                   j1.x - i1.x + c1.x, j1.y - i1.y + c1.y,
                   j1.z - i1.z + c1.z, j1.w - i1.w + c1.w};
    float rv[8];
    #pragma unroll
    for (int k = 0; k < 8; ++k) {
      float x = xv[k];
      float ax = fabsf(x);
      float e = __expf(-2.f * ax);
      float r = __fdividef(1.f - e, 1.f + e);
      rv[k] = copysignf(r, x);
    }
    V8U out;
    #pragma unroll
    for (int k = 0; k < 4; ++k) {
      PkU pu;
      pu.h = __builtin_amdgcn_cvt_pkrtz(rv[2 * k], rv[2 * k + 1]);
      out.u[k] = (int)pu.u;
    }
    *(v8h*)(hG + (size_t)p * 512 + o0) = out.v;
  }
}

// ---------------------------------------------------------------------------
// K4: lie[p][n] = h[p] . W2[n] + b2[n], f16 MFMA GEMM (M=pairs, N=120pad128,
// K=256).  128 pairs/block (8 waves), W2 staged per K-half from the
// PRE-CONVERTED f16 copy as pure v8h copies (no cvt, ~4 ld+st per thread).
// lie written f16 to slot bytes [512,752).
// ---------------------------------------------------------------------------
__global__ __launch_bounds__(512) void lie_kernel(
    const _Float16* __restrict__ w2h, const float* __restrict__ b2g,
    float* __restrict__ Tg) {
  __shared__ _Float16 w2t[128 * 136];
  int t = threadIdx.x, lane = t & 63;
  int wu = __builtin_amdgcn_readfirstlane(t >> 6);
  int pbase = blockIdx.x * 128 + wu * 16;
  int nn = lane & 15, q = lane >> 4;
  const _Float16* hf = (const _Float16*)Tg;

  // zero pad rows 120..127 once (never overwritten by staging)
  for (int idx = t; idx < 1088; idx += 512) w2t[16320 + idx] = (_Float16)0.f;

  v4f acc[8];
  #pragma unroll
  for (int tt = 0; tt < 8; ++tt) acc[tt] = (v4f){0.f, 0.f, 0.f, 0.f};

  const _Float16* hrow = hf + (size_t)(pbase + nn) * 512;
  for (int khalf = 0; khalf < 2; ++khalf) {
    __syncthreads();
    // stage W2 K-half: 120 rows x 128 cols f16 = 1920 v8h units
    for (int idx = t; idx < 1920; idx += 512) {
      int row = idx >> 4, cu = (idx & 15) * 8;
      *(v8h*)(w2t + row * 136 + cu) =
          *(const v8h*)(w2h + row * 256 + khalf * 128 + cu);
    }
    __syncthreads();
    #pragma unroll
    for (int ks = 0; ks < 4; ++ks) {
      v8h ah = *(const v8h*)(hrow + khalf * 128 + ks * 32 + 8 * q);
      #pragma unroll
      for (int tt = 0; tt < 8; ++tt) {
        const v8h bf = *(const v8h*)(w2t + (16 * tt + nn) * 136 + ks * 32 + 8 * q);
        acc[tt] = __builtin_amdgcn_mfma_f32_16x16x32_f16(ah, bf, acc[tt], 0, 0, 0);
      }
    }
  }

  _Float16* hw = (_Float16*)Tg;
  #pragma unroll
  for (int tt = 0; tt < 8; ++tt) {
    int n16 = 16 * tt + nn;
    if (n16 < 120) {
      float bb = b2g[n16];
      #pragma unroll
      for (int reg = 0; reg < 4; ++reg) {
        size_t p = (size_t)(pbase + 4 * q + reg);
        hw[p * 512 + 256 + n16] = (_Float16)(acc[tt][reg] + bb);
      }
    }
  }
}

// ---------------------------------------------------------------------------
// K5: per-pair T = expm(skew(lie)) via Paterson-Stockmeyer even/odd split:
//   exp(A) = C(B) + A*Q(B),  B = A^2 (SYMMETRIC -> one bpermute transform
//   serves as BOTH MFMA operands).
// Epilogue computes attn-weighted transported partials (per-block) to `part`.
// ---------------------------------------------------------------------------
__device__ __forceinline__ void split8(const float* x, v8h& hi, v8h& lo) {
  union U { v8h v; v2hf p[4]; } H, L;
  #pragma unroll
  for (int i = 0; i < 4; ++i) {
    float a = x[2 * i], b = x[2 * i + 1];
    v2hf h = __builtin_amdgcn_cvt_pkrtz(a, b);
    float ra = (float)h[0], rb = (float)h[1];
    v2hf l = __builtin_amdgcn_cvt_pkrtz(a - ra, b - rb);
    H.p[i] = h;
    L.p[i] = l;
  }
  hi = H.v;
  lo = L.v;
}

__device__ __forceinline__ int lie_idx(int rr, int cc) {
  return 15 * rr - ((rr * (rr - 1)) >> 1) + cc - rr - 1;
}

__global__ __launch_bounds__(256) void expm_kernel(
    float* __restrict__ Tg, const float* __restrict__ attn,
    const float* __restrict__ xm, float* __restrict__ part) {
  __shared__ char lds[12288] __attribute__((aligned(16)));
  __shared__ float sred[4][16];
  int t = threadIdx.x, lane = t & 63;
  int wu = __builtin_amdgcn_readfirstlane(t >> 6);
  int pbase = blockIdx.x * 8 + wu * 2;
  int nn = lane & 15, q = lane >> 4, b8 = (q & 1) * 8;
  char* wb = lds + wu * 3072;
  _Float16* lieS = (_Float16*)wb;   // [2][128] f16
  float* ErB = (float*)(wb + 512);  // [2][320] f32 (16 rows x stride 20)
  const _Float16* hf = (const _Float16*)Tg;

  int idxA = ((2 * (q & 1)) * 16 + nn) * 4;
  int idxB = idxA + 64;

  // ---- load lie, compute per-pair scaling ----
  float scv[2];
  int sv[2];
  #pragma unroll
  for (int j = 0; j < 2; ++j) {
    size_t p = (size_t)(pbase + j);
    _Float16 a0 = (lane < 120) ? hf[p * 512 + 256 + lane] : (_Float16)0.f;
    _Float16 a1 = (lane < 56) ? hf[p * 512 + 320 + lane] : (_Float16)0.f;
    lieS[j * 128 + lane] = a0;
    lieS[j * 128 + 64 + lane] = a1;
    float f0 = (float)a0, f1 = (float)a1;
    float s2 = f0 * f0 + f1 * f1;
    #pragma unroll
    for (int off = 1; off < 64; off <<= 1) s2 += __shfl_xor(s2, off, 64);
    float bound = sqrtf(s2);  // ||A||_2 <= sqrt(sum lie^2) for skew
    int s = 0;
    while (bound > 1.0f && s < 12) { bound *= 0.5f; s++; }
    sv[j] = __builtin_amdgcn_readfirstlane(s);
    scv[j] = ldexpf(1.0f, -s);
  }
  asm volatile("s_waitcnt lgkmcnt(0)" ::: "memory");

  // ---- A-frags (f16-exact, [X|X] dup) + f32 C-layout rows of A ----
  V8U Apk[2], BfA[2];
  v4f Af[2];
  #pragma unroll
  for (int j = 0; j < 2; ++j) {
    const _Float16* lp = lieS + j * 128;
    float sc = scv[j];
    float av[8];
    #pragma unroll
    for (int jj = 0; jj < 8; ++jj) {
      int c = b8 + jj;
      int rr = min(nn, c), c2 = max(nn, c);
      float lv = (c == nn) ? 0.f : (float)lp[lie_idx(rr, c2)];
      av[jj] = (c == nn) ? 0.f : ((c > nn) ? lv : -lv) * sc;
    }
    #pragma unroll
    for (int i = 0; i < 4; ++i) {
      PkU u;
      u.h = __builtin_amdgcn_cvt_pkrtz(av[2 * i], av[2 * i + 1]);
      Apk[j].u[i] = (int)u.u;
      BfA[j].u[i] = Apk[j].u[i] ^ 0x80008000;  // B-frag of A (= -A rows)
    }
    #pragma unroll
    for (int reg = 0; reg < 4; ++reg) {
      int r = 4 * q + reg;
      int rr = min(r, nn), c2 = max(r, nn);
      float lv = (r == nn) ? 0.f : (float)lp[lie_idx(rr, c2)];
      Af[j][reg] = (r == nn) ? 0.f : ((nn > r) ? lv : -lv) * sc;
    }
  }

  // identity frags in gather layout, pre-scaled by combo coefficients
  V8U IC1, IC2;
  #pragma unroll
  for (int i = 0; i < 4; ++i) {
    float d0 = (b8 + 2 * i == nn) ? 1.f : 0.f;
    float d1 = (b8 + 2 * i + 1 == nn) ? 1.f : 0.f;
    PkU u1, u2;
    u1.h = __builtin_amdgcn_cvt_pkrtz(10.666667f * d0, 10.666667f * d1);   // 256/24
    u2.h = __builtin_amdgcn_cvt_pkrtz(2.1333333f * d0, 2.1333333f * d1);   // 256/120
    IC1.u[i] = (int)u1.u;
    IC2.u[i] = (int)u2.u;
  }

  v4f z4 = {0.f, 0.f, 0.f, 0.f};

  // ---- MFMA1: cB = 2*B (B = A^2) ----
  v4f cB[2];
  #pragma unroll
  for (int j = 0; j < 2; ++j)
    cB[j] = __builtin_amdgcn_mfma_f32_16x16x32_f16(Apk[j].v, BfA[j].v, z4, 0, 0, 0);

  // ---- transform 1: fB = gather(2B) ----
  V8U fB[2];
  #pragma unroll
  for (int j = 0; j < 2; ++j) {
    PkU u0, u1;
    u0.h = __builtin_amdgcn_cvt_pkrtz(cB[j][0], cB[j][1]);
    u1.h = __builtin_amdgcn_cvt_pkrtz(cB[j][2], cB[j][3]);
    fB[j].u[0] = __builtin_amdgcn_ds_bpermute(idxA, (int)u0.u);
    fB[j].u[1] = __builtin_amdgcn_ds_bpermute(idxA, (int)u1.u);
    fB[j].u[2] = __builtin_amdgcn_ds_bpermute(idxB, (int)u0.u);
    fB[j].u[3] = __builtin_amdgcn_ds_bpermute(idxB, (int)u1.u);
  }

  // ---- MFMA2: cB2 = 8*B^2 ----
  v4f cB2[2];
  #pragma unroll
  for (int j = 0; j < 2; ++j)
    cB2[j] = __builtin_amdgcn_mfma_f32_16x16x32_f16(fB[j].v, fB[j].v, z4, 0, 0, 0);

  // ---- transform 2: fB2 = gather(8*B^2) ----
  V8U fB2[2];
  #pragma unroll
  for (int j = 0; j < 2; ++j) {
    PkU u0, u1;
    u0.h = __builtin_amdgcn_cvt_pkrtz(cB2[j][0], cB2[j][1]);
    u1.h = __builtin_amdgcn_cvt_pkrtz(cB2[j][2], cB2[j][3]);
    fB2[j].u[0] = __builtin_amdgcn_ds_bpermute(idxA, (int)u0.u);
    fB2[j].u[1] = __builtin_amdgcn_ds_bpermute(idxA, (int)u1.u);
    fB2[j].u[2] = __builtin_amdgcn_ds_bpermute(idxB, (int)u0.u);
    fB2[j].u[3] = __builtin_amdgcn_ds_bpermute(idxB, (int)u1.u);
  }

  // ---- combo frags in f16 domain ----
  v8h k1a = splat8(7.9365079e-4f);   // 32/40320
  v8h k1b = splat8(0.17777778f);     // 128/720
  v8h k2a = splat8(8.8183422e-5f);   // 32/362880
  v8h k2b = splat8(2.5396825e-2f);   // 128/5040
  V8U M1[2], M2[2];
  #pragma unroll
  for (int j = 0; j < 2; ++j) {
    M1[j].v = fB2[j].v * k1a + (fB[j].v * k1b + IC1.v);
    M2[j].v = fB2[j].v * k2a + (fB[j].v * k2b + IC2.v);
  }

  // ---- MFMA3/4: high parts of C and Q; fold exact low-order f32 terms ----
  v4f Cc[2], Qc[2];
  #pragma unroll
  for (int j = 0; j < 2; ++j) {
    v4f c3m = __builtin_amdgcn_mfma_f32_16x16x32_f16(M1[j].v, fB2[j].v, z4, 0, 0, 0);
    v4f c4m = __builtin_amdgcn_mfma_f32_16x16x32_f16(M2[j].v, fB2[j].v, z4, 0, 0, 0);
    #pragma unroll
    for (int reg = 0; reg < 4; ++reg) {
      float dg = (4 * q + reg == nn) ? 1.f : 0.f;
      Cc[j][reg] = fmaf(c3m[reg], 2.44140625e-4f,
                        fmaf(cB[j][reg], 0.25f, dg + Af[j][reg]));
      Qc[j][reg] = fmaf(c4m[reg], 2.44140625e-4f, cB[j][reg] * 0.083333333f);
    }
  }

  // ---- transform 3: fQ = gather(Qr) ----
  V8U fQ[2];
  #pragma unroll
  for (int j = 0; j < 2; ++j) {
    PkU u0, u1;
    u0.h = __builtin_amdgcn_cvt_pkrtz(Qc[j][0], Qc[j][1]);
    u1.h = __builtin_amdgcn_cvt_pkrtz(Qc[j][2], Qc[j][3]);
    fQ[j].u[0] = __builtin_amdgcn_ds_bpermute(idxA, (int)u0.u);
    fQ[j].u[1] = __builtin_amdgcn_ds_bpermute(idxA, (int)u1.u);
    fQ[j].u[2] = __builtin_amdgcn_ds_bpermute(idxB, (int)u0.u);
    fQ[j].u[3] = __builtin_amdgcn_ds_bpermute(idxB, (int)u1.u);
  }

  // ---- MFMA5: E = Cc + A*Qr ----
  v4f E[2];
  #pragma unroll
  for (int j = 0; j < 2; ++j) {
    v4f c5 = __builtin_amdgcn_mfma_f32_16x16x32_f16(Apk[j].v, fQ[j].v, z4, 0, 0, 0);
    E[j] = Cc[j] + c5 * 0.5f;
  }

  // ---- squarings: E <- E*E ----
  int smax = max(sv[0], sv[1]);
  for (int it = 0; it < smax; ++it) {
    #pragma unroll
    for (int j = 0; j < 2; ++j) {
      if (it < sv[j]) {
        float* Erp = ErB + j * 320;
        PkU u0, u1;
        u0.h = __builtin_amdgcn_cvt_pkrtz(E[j][0], E[j][1]);
        u1.h = __builtin_amdgcn_cvt_pkrtz(E[j][2], E[j][3]);
        V8U bfe;
        bfe.u[0] = __builtin_amdgcn_ds_bpermute(idxA, (int)u0.u);
        bfe.u[1] = __builtin_amdgcn_ds_bpermute(idxA, (int)u1.u);
        bfe.u[2] = __builtin_amdgcn_ds_bpermute(idxB, (int)u0.u);
        bfe.u[3] = __builtin_amdgcn_ds_bpermute(idxB, (int)u1.u);
        #pragma unroll
        for (int reg = 0; reg < 4; ++reg)
          Erp[(4 * q + reg) * 20 + nn] = E[j][reg];
        asm volatile("s_waitcnt lgkmcnt(0)" ::: "memory");
        float4 a0 = *(const float4*)(Erp + nn * 20 + b8);
        float4 a1 = *(const float4*)(Erp + nn * 20 + b8 + 4);
        float xa[8] = {a0.x, a0.y, a0.z, a0.w, a1.x, a1.y, a1.z, a1.w};
        v8h ahi, alo;
        split8(xa, ahi, alo);
        v8h Ecat = (q < 2) ? ahi : alo;
        v4f z = {0.f, 0.f, 0.f, 0.f};
        E[j] = __builtin_amdgcn_mfma_f32_16x16x32_f16(Ecat, bfe.v, z, 0, 0, 0);
      }
    }
  }

  // ---- store T + fused attn-weighted transported partials ----
  float pacc[4] = {0.f, 0.f, 0.f, 0.f};
  #pragma unroll
  for (int j = 0; j < 2; ++j) {
    int p = pbase + j;
    float* dst = Tg + (size_t)p * 256;
    #pragma unroll
    for (int reg = 0; reg < 4; ++reg)
      dst[(4 * q + reg) * 16 + nn] = E[j][reg];
    int b = p >> 14, i = p & 127;
    float xv = xm[((b << 7) + i) * 16 + nn];
    float aw = attn[(size_t)p] * xv;
    #pragma unroll
    for (int reg = 0; reg < 4; ++reg)
      pacc[reg] = fmaf(aw, E[j][reg], pacc[reg]);
  }
  #pragma unroll
  for (int reg = 0; reg < 4; ++reg) {
    #pragma unroll
    for (int off = 1; off < 16; off <<= 1)
      pacc[reg] += __shfl_xor(pacc[reg], off, 64);
  }
  if (nn == 0) {
    #pragma unroll
    for (int reg = 0; reg < 4; ++reg) sred[wu][4 * q + reg] = pacc[reg];
  }
  __syncthreads();
  if (t < 16)
    part[(size_t)blockIdx.x * 16 + t] =
        sred[0][t] + sred[1][t] + sred[2][t] + sred[3][t];
}

// ---------------------------------------------------------------------------
// K6: settled[bj] = sum of 16 per-block partials; out = settled @ Wo^T + bo
// ---------------------------------------------------------------------------
__global__ __launch_bounds__(64) void settle_fin_kernel(
    const float* __restrict__ part, const float* __restrict__ Wo,
    const float* __restrict__ bo, float* __restrict__ outp) {
  int bj = blockIdx.x, t = threadIdx.x;
  int r = t & 15, e0 = t >> 4;
  const float* pb = part + (size_t)bj * 256;
  float s = pb[e0 * 16 + r] + pb[(e0 + 4) * 16 + r] +
            pb[(e0 + 8) * 16 + r] + pb[(e0 + 12) * 16 + r];
  __shared__ float sf[64];
  sf[t] = s;
  __syncthreads();
  if (t < 16) sf[t] = sf[t] + sf[16 + t] + sf[32 + t] + sf[48 + t];
  __syncthreads();
  if (t < 16) {
    float o = bo[t];
    const float* wr = Wo + t * 16;
    #pragma unroll
    for (int c = 0; c < 16; ++c) o = fmaf(wr[c], sf[c], o);
    outp[bj * 16 + t] = o;
  }
}

// ---------------------------------------------------------------------------
extern "C" void kernel_launch(void* const* d_in, const int* in_sizes, int n_in,
                              void* d_out, int out_size, void* d_ws,
                              size_t ws_size, hipStream_t stream) {
  const float* xl = (const float*)d_in[0];
  const float* xm = (const float*)d_in[1];
  const float* Wq = (const float*)d_in[2];
  const float* bq = (const float*)d_in[3];
  const float* Wk = (const float*)d_in[4];
  const float* bk = (const float*)d_in[5];
  const float* W1 = (const float*)d_in[6];
  const float* b1 = (const float*)d_in[7];
  const float* W2 = (const float*)d_in[8];
  const float* b2 = (const float*)d_in[9];
  const float* Wo = (const float*)d_in[10];
  const float* bo = (const float*)d_in[11];
  float* outp = (float*)d_out;
  float* Tg = outp + 8192;  // [65536][256]: h f16 bytes [0,512), lie f16
                            // bytes [512,752), then overwritten with T fp32
  float* wsf = (float*)d_ws;
  float* Q = wsf;                // 65536
  float* K = wsf + 65536;        // 65536
  float* attn = wsf + 131072;    // 65536
  // Aliasing (stream-serial lifetimes, footprint stays at 1.25 MB):
  //   w2h (f16 W2 copy, 7680 floats) lives in Q: Q dead after attn (disp 2),
  //     w2h written disp 3, last read disp 5.
  //   u (x@W1^T, 131072 floats) / part (131072 floats): u written disp 1,
  //     last read disp 4; part first written disp 6.
  _Float16* w2h = (_Float16*)Q;
  float* u = wsf + 196608;
  float* part = wsf + 196608;

  hipLaunchKernelGGL(qku_kernel, dim3(512), dim3(512), 0, stream, xl, Wq, bq, Wk, bk, W1, Q, K, u);
  hipLaunchKernelGGL(attn_kernel, dim3(512), dim3(128), 0, stream, Q, K, attn);
  hipLaunchKernelGGL(w2prep_kernel, dim3(30), dim3(256), 0, stream, W2, w2h);
  hipLaunchKernelGGL(h_from_u_kernel, dim3(2048), dim3(256), 0, stream, u, b1, (_Float16*)Tg);
  hipLaunchKernelGGL(lie_kernel, dim3(512), dim3(512), 0, stream, w2h, b2, Tg);
  hipLaunchKernelGGL(expm_kernel, dim3(8192), dim3(256), 0, stream, Tg, attn, xm, part);
  hipLaunchKernelGGL(settle_fin_kernel, dim3(512), dim3(64), 0, stream, part, Wo, bo, outp);
}